// Round 8
// baseline (619.713 us; speedup 1.0000x reference)
//
#include <hip/hip_runtime.h>
#include <hip/hip_bf16.h>
#include <math.h>

// ---------------- problem constants ----------------
#define N_NODES 10000
#define N_EDGES0 160000
#define E_TOT (N_EDGES0 + N_NODES)   // + self loops
#define H1 4
#define C1 512
#define F1 2048                      // H1*C1
#define IN_DIM 768
#define C2 768
#define NEG_SLOPE 0.2f

typedef _Float16 f16x8 __attribute__((ext_vector_type(8)));
typedef _Float16 f16x4 __attribute__((ext_vector_type(4)));
typedef float f32x4 __attribute__((ext_vector_type(4)));

typedef __attribute__((address_space(1))) const void* gas_ptr;
typedef __attribute__((address_space(3))) void* las_ptr;
static __device__ __forceinline__ void gload16(const void* g, void* l) {
  __builtin_amdgcn_global_load_lds((gas_ptr)g, (las_ptr)l, 16, 0, 0);
}

// Monotonic float<->unsigned encoding so atomicMax works for signed floats.
static __device__ __forceinline__ unsigned enc_f(float v) {
  unsigned u = __float_as_uint(v);
  return (u & 0x80000000u) ? ~u : (u | 0x80000000u);
}
static __device__ __forceinline__ float dec_f(unsigned u) {
  return (u & 0x80000000u) ? __uint_as_float(u ^ 0x80000000u)
                           : __uint_as_float(~u);
}

// edge e -> (src, dst); e >= N_EDGES0 are the implicit self-loops
static __device__ __forceinline__ void edge_sd(const int* __restrict__ ei, int e,
                                               int& s, int& d) {
  if (e < N_EDGES0) { s = ei[e]; d = ei[N_EDGES0 + e]; }
  else { s = e - N_EDGES0; d = s; }
}

// ---------------- W [K][N] fp32 -> W^T [N][K] f16 hi/lo ---------------------
__global__ void tsplit_k(const float* __restrict__ W, _Float16* __restrict__ hi,
                         _Float16* __restrict__ lo, int K, int N) {
  __shared__ float tile[32][33];
  const int nb = blockIdx.x * 32, kb = blockIdx.y * 32;
  const int tx = threadIdx.x, ty = threadIdx.y;  // 32 x 8
  for (int r = ty; r < 32; r += 8)
    tile[r][tx] = W[(size_t)(kb + r) * N + nb + tx];
  __syncthreads();
  for (int r = ty; r < 32; r += 8) {
    float v = tile[tx][r];  // = W[kb+tx][nb+r]
    _Float16 h = (_Float16)v;
    hi[(size_t)(nb + r) * K + kb + tx] = h;
    lo[(size_t)(nb + r) * K + kb + tx] = (_Float16)(v - (float)h);
  }
}

// ---- layer-1 attn vectors projected into x-space: ws[h,k] = sum_c W1[k,h*C1+c]*a[h,c]
__global__ void proj_attn_k(const float* __restrict__ W1,
                            const float* __restrict__ as1,
                            const float* __restrict__ ad1,
                            float* __restrict__ ws, float* __restrict__ wd) {
  int wv = (blockIdx.x * blockDim.x + threadIdx.x) >> 6;
  int lane = threadIdx.x & 63;
  if (wv >= H1 * IN_DIM) return;
  int h = wv / IN_DIM, k = wv - h * IN_DIM;
  const float* wrow = W1 + (size_t)k * F1 + h * C1;
  const float* sa = as1 + h * C1;
  const float* da = ad1 + h * C1;
  float ss = 0.f, sd = 0.f;
  for (int c = lane; c < C1; c += 64) {
    float v = wrow[c];
    ss = fmaf(v, sa[c], ss);
    sd = fmaf(v, da[c], sd);
  }
#pragma unroll
  for (int o = 32; o; o >>= 1) { ss += __shfl_xor(ss, o); sd += __shfl_xor(sd, o); }
  if (lane == 0) { ws[(size_t)h * IN_DIM + k] = ss; wd[(size_t)h * IN_DIM + k] = sd; }
}

// ---- layer-1 logits from raw x: als[n,h] = x[n,:] . ws[h,:]
__global__ void logits1_k(const float* __restrict__ x,
                          const float* __restrict__ ws, const float* __restrict__ wd,
                          float* __restrict__ als, float* __restrict__ ald) {
  int n = (blockIdx.x * blockDim.x + threadIdx.x) >> 6;
  int lane = threadIdx.x & 63;
  if (n >= N_NODES) return;
  const float* xp = x + (size_t)n * IN_DIM;
  float ss[H1] = {0.f, 0.f, 0.f, 0.f}, sd[H1] = {0.f, 0.f, 0.f, 0.f};
  for (int k = lane; k < IN_DIM; k += 64) {
    float xv = xp[k];
#pragma unroll
    for (int h = 0; h < H1; h++) {
      ss[h] = fmaf(xv, ws[h * IN_DIM + k], ss[h]);
      sd[h] = fmaf(xv, wd[h * IN_DIM + k], sd[h]);
    }
  }
#pragma unroll
  for (int h = 0; h < H1; h++)
#pragma unroll
    for (int o = 32; o; o >>= 1) { ss[h] += __shfl_xor(ss[h], o); sd[h] += __shfl_xor(sd[h], o); }
  if (lane == 0) {
#pragma unroll
    for (int h = 0; h < H1; h++) {
      als[(size_t)n * H1 + h] = ss[h];
      ald[(size_t)n * H1 + h] = sd[h];
    }
  }
}

// ---------------- split-f16 MFMA GEMM: C[M,N] = A[M,K] @ Bt[N,K]^T ----------
// T3 minimum 2-phase: BK=32, DOUBLE-buffered LDS (2x32KB = 64KB -> still
// 2 blocks/CU). Per K-step: issue next-tile global_load_lds FIRST, then
// ds_read+MFMA on current buffer, then ONE vmcnt(0)+barrier. The prefetch
// has the whole compute phase (~500cyc) to land -> drain stall ~0.
// Swizzle (verified 0-conflict, R4): LDS granule (row,g') holds global
// granule (row,(g'-(row>>1))&3); source gsrc=((lane&3)-((lane>>3)&3))&3;
// read lgs=(lg+(lr>>1))&3.  XCD remap (m204 bijective) kept (FETCH halved).
template <bool SPLITOUT>
__global__ __launch_bounds__(256) void gemm_sf16(
    const _Float16* __restrict__ Ahi, const _Float16* __restrict__ Alo,
    const _Float16* __restrict__ Bhi, const _Float16* __restrict__ Blo,
    int M, int N, int K, int lda, int nch, int nbx, int nwg,
    float* __restrict__ C, const float* __restrict__ bias,
    _Float16* __restrict__ ohi, _Float16* __restrict__ olo,
    const float* __restrict__ asrc, const float* __restrict__ adst,
    float* __restrict__ als, float* __restrict__ ald, int Hh, int Cdim) {
  // [buf][arr: 0=Ahi 1=Alo 2=Bhi 3=Blo][128 rows x 32 f16]
  __shared__ _Float16 sbuf[2][4][128 * 32];

  // bijective XCD-chunked remap (nwg need not be %8)
  const int orig = blockIdx.x;
  const int q = nwg >> 3, rr = nwg & 7;
  const int xcd = orig & 7, pos = orig >> 3;
  const int wgid = (xcd < rr ? xcd * (q + 1) : rr * (q + 1) + (xcd - rr) * q) + pos;
  const int bx = wgid % nbx, by = wgid / nbx;
  const int m0 = by * 128, n0 = bx * 128;

  const int t = threadIdx.x;
  const int w = t >> 6, lane = t & 63;
  const size_t hofs = (size_t)(n0 / nch) * K;

  // staging: chunk0 = LDS bytes [w*1024 + lane*16), chunk1 = +4096 (64B rows)
  const int o0 = w * 1024 + lane * 16;
  const int o1 = o0 + 4096;
  const int ma0 = o0 >> 6, ma1 = o1 >> 6;
  const int gsrc = ((lane & 3) - ((lane >> 3) & 3)) & 3;  // inverse-swizzled src granule
  const int rA0 = min(m0 + ma0, M - 1), rA1 = min(m0 + ma1, M - 1);
  const size_t gA0 = (size_t)rA0 * lda + hofs + gsrc * 8;
  const size_t gA1 = (size_t)rA1 * lda + hofs + gsrc * 8;
  const size_t gB0 = (size_t)(n0 + ma0) * K + gsrc * 8;
  const size_t gB1 = (size_t)(n0 + ma1) * K + gsrc * 8;

  const int wr = w >> 1, wc = w & 1;
  const int lr = lane & 15, lg = lane >> 4;
  const int lgs = (lg + (lr >> 1)) & 3;        // swizzled read granule
  const int aoff = (wr * 64 + lr) * 32 + lgs * 8;
  const int boff = (wc * 64 + lr) * 32 + lgs * 8;

  f32x4 acc[4][4];
#pragma unroll
  for (int i = 0; i < 4; i++)
#pragma unroll
    for (int j = 0; j < 4; j++) acc[i][j] = (f32x4)(0.f);

  auto STAGE = [&](int b, int k0) {
    char* a0 = (char*)&sbuf[b][0][0] + w * 1024;
    char* a1 = (char*)&sbuf[b][1][0] + w * 1024;
    char* b0 = (char*)&sbuf[b][2][0] + w * 1024;
    char* b1 = (char*)&sbuf[b][3][0] + w * 1024;
    gload16(Ahi + gA0 + k0, a0);
    gload16(Ahi + gA1 + k0, a0 + 4096);
    gload16(Alo + gA0 + k0, a1);
    gload16(Alo + gA1 + k0, a1 + 4096);
    gload16(Bhi + gB0 + k0, b0);
    gload16(Bhi + gB1 + k0, b0 + 4096);
    gload16(Blo + gB0 + k0, b1);
    gload16(Blo + gB1 + k0, b1 + 4096);
  };

  const int NT = K >> 5;   // K/32 steps
  STAGE(0, 0);
  __syncthreads();         // prologue drain: buf0 ready

  int cur = 0;
  for (int ts = 0; ts < NT; ++ts) {
    if (ts + 1 < NT) STAGE(cur ^ 1, (ts + 1) * 32);  // prefetch BEFORE compute

    const _Float16* pAh = &sbuf[cur][0][0];
    const _Float16* pAl = &sbuf[cur][1][0];
    const _Float16* pBh = &sbuf[cur][2][0];
    const _Float16* pBl = &sbuf[cur][3][0];
    f16x8 ah[4], al[4], bh[4], bl[4];
#pragma unroll
    for (int i = 0; i < 4; i++) {
      ah[i] = *(const f16x8*)&pAh[aoff + i * 16 * 32];
      al[i] = *(const f16x8*)&pAl[aoff + i * 16 * 32];
      bh[i] = *(const f16x8*)&pBh[boff + i * 16 * 32];
      bl[i] = *(const f16x8*)&pBl[boff + i * 16 * 32];
    }
#pragma unroll
    for (int i = 0; i < 4; i++)
#pragma unroll
      for (int j = 0; j < 4; j++) {
        acc[i][j] = __builtin_amdgcn_mfma_f32_16x16x32_f16(ah[i], bh[j], acc[i][j], 0, 0, 0);
        acc[i][j] = __builtin_amdgcn_mfma_f32_16x16x32_f16(ah[i], bl[j], acc[i][j], 0, 0, 0);
        acc[i][j] = __builtin_amdgcn_mfma_f32_16x16x32_f16(al[i], bh[j], acc[i][j], 0, 0, 0);
      }

    __syncthreads();  // ONE barrier/step: drains prefetch (covered by compute)
                      // and guarantees cur^1 is compute-free before next STAGE
    cur ^= 1;
  }

  // C/D layout: col = lane&15, row = (lane>>4)*4 + reg  [m89/m91 verified]
  if constexpr (SPLITOUT) {
    // bias + ELU + f16 hi/lo split (feeds next GEMM's A)
#pragma unroll
    for (int j = 0; j < 4; j++) {
      const int col = n0 + wc * 64 + j * 16 + lr;
      const float bv = bias[col];
#pragma unroll
      for (int i = 0; i < 4; i++) {
        const int rbase = m0 + wr * 64 + i * 16 + lg * 4;
#pragma unroll
        for (int r = 0; r < 4; r++) {
          const int row = rbase + r;
          if (row < M) {
            float o = acc[i][j][r] + bv;
            o = o > 0.f ? o : expm1f(o);
            _Float16 hv = (_Float16)o;
            ohi[(size_t)row * N + col] = hv;
            olo[(size_t)row * N + col] = (_Float16)(o - (float)hv);
          }
        }
      }
    }
  } else {
#pragma unroll
    for (int i = 0; i < 4; i++)
#pragma unroll
      for (int j = 0; j < 4; j++) {
        const int col = n0 + wc * 64 + j * 16 + lr;
        const int rbase = m0 + wr * 64 + i * 16 + lg * 4;
#pragma unroll
        for (int r = 0; r < 4; r++) {
          int row = rbase + r;
          if (row < M) C[(size_t)row * N + col] = acc[i][j][r];
        }
      }

    // fused attention logits (128-col tile lies in one head)
    const int head = n0 / Cdim;
    const int cbase = n0 - head * Cdim + wc * 64 + lr;
    float asv[4], adv[4];
#pragma unroll
    for (int j = 0; j < 4; j++) {
      asv[j] = asrc[(size_t)head * Cdim + cbase + j * 16];
      adv[j] = adst[(size_t)head * Cdim + cbase + j * 16];
    }
#pragma unroll
    for (int i = 0; i < 4; i++) {
      const int rbase = m0 + wr * 64 + i * 16 + lg * 4;
#pragma unroll
      for (int r = 0; r < 4; r++) {
        float ss = 0.f, sd = 0.f;
#pragma unroll
        for (int j = 0; j < 4; j++) {
          float v = acc[i][j][r];
          ss = fmaf(v, asv[j], ss);
          sd = fmaf(v, adv[j], sd);
        }
#pragma unroll
        for (int o = 8; o; o >>= 1) {
          ss += __shfl_xor(ss, o);
          sd += __shfl_xor(sd, o);
        }
        if (lr == 0 && rbase + r < M) {
          atomicAdd(&als[(size_t)(rbase + r) * Hh + head], ss);
          atomicAdd(&ald[(size_t)(rbase + r) * Hh + head], sd);
        }
      }
    }
  }
}

// ---------------- edge softmax passes ----------------
__global__ void edge_max_k(const int* __restrict__ ei,
                           const float* __restrict__ als,
                           const float* __restrict__ ald,
                           float* __restrict__ ev, unsigned* __restrict__ menc,
                           int Hh) {
  int idx = blockIdx.x * blockDim.x + threadIdx.x;
  if (idx >= E_TOT * Hh) return;
  int e = idx / Hh, hh = idx - e * Hh;
  int s, d; edge_sd(ei, e, s, d);
  float x = als[s * Hh + hh] + ald[d * Hh + hh];
  float v = x > 0.f ? x : NEG_SLOPE * x;   // leaky_relu
  ev[idx] = v;
  atomicMax(&menc[d * Hh + hh], enc_f(v));
}

// writes exp values in CSR (dst-sorted) order -> contiguous reads in aggregation
__global__ void edge_exp_k(const int* __restrict__ ei,
                           const unsigned* __restrict__ menc,
                           const float* __restrict__ ev,
                           const int* __restrict__ csr_pos,
                           float* __restrict__ evs, float* __restrict__ denom,
                           int Hh) {
  int idx = blockIdx.x * blockDim.x + threadIdx.x;
  if (idx >= E_TOT * Hh) return;
  int e = idx / Hh, hh = idx - e * Hh;
  int s, d; edge_sd(ei, e, s, d);
  float m = dec_f(menc[d * Hh + hh]);
  float ex = expf(ev[idx] - m);
  evs[(size_t)csr_pos[e] * Hh + hh] = ex;
  atomicAdd(&denom[d * Hh + hh], ex);
}

// ---------------- CSR build (dst-sorted) ----------------
__global__ void hist_k(const int* __restrict__ ei, int* __restrict__ count) {
  int e = blockIdx.x * blockDim.x + threadIdx.x;
  if (e >= E_TOT) return;
  int s, d; edge_sd(ei, e, s, d);
  atomicAdd(&count[d], 1);
}

__global__ __launch_bounds__(1024) void scan_k(const int* __restrict__ count,
                                               int* __restrict__ rowstart,
                                               int N, int total) {
  __shared__ int sums[1024];
  __shared__ int carry_s;
  int t = threadIdx.x;
  if (t == 0) carry_s = 0;
  __syncthreads();
  for (int base = 0; base < N; base += 1024) {
    int i = base + t;
    int c = (i < N) ? count[i] : 0;
    sums[t] = c;
    __syncthreads();
    for (int off = 1; off < 1024; off <<= 1) {
      int v = (t >= off) ? sums[t - off] : 0;
      __syncthreads();
      sums[t] += v;
      __syncthreads();
    }
    int carry = carry_s;
    if (i < N) rowstart[i] = carry + sums[t] - c;  // exclusive
    __syncthreads();
    if (t == 1023) carry_s = carry + sums[1023];
    __syncthreads();
  }
  if (t == 0) rowstart[N] = total;
}

__global__ void scatter_k(const int* __restrict__ ei,
                          const int* __restrict__ rowstart,
                          int* __restrict__ cursor,
                          int* __restrict__ csr_src, int* __restrict__ csr_pos) {
  int e = blockIdx.x * blockDim.x + threadIdx.x;
  if (e >= E_TOT) return;
  int s, d; edge_sd(ei, e, s, d);
  int pos = rowstart[d] + atomicAdd(&cursor[d], 1);
  csr_src[pos] = s;
  csr_pos[e] = pos;   // inverse permutation (edge -> CSR slot)
}

// ---- layer-1 aggregation of RAW x (per head): xa[n,h,:] = sum alpha[e,h] x[s,:]
// writes f16 hi/lo [N][H1][IN_DIM] (GEMM1 A, lda = H1*IN_DIM)
__global__ __launch_bounds__(192) void aggregate_x_k(
    const float* __restrict__ x, const float* __restrict__ evs,
    const float* __restrict__ denom, const int* __restrict__ rowstart,
    const int* __restrict__ csr_src,
    _Float16* __restrict__ ohi, _Float16* __restrict__ olo) {
  const int n = blockIdx.x;
  const int f0 = threadIdx.x * 4;  // < 768
  float inv[H1];
#pragma unroll
  for (int h = 0; h < H1; h++) inv[h] = 1.f / (denom[n * H1 + h] + 1e-16f);
  float acc[H1][4];
#pragma unroll
  for (int h = 0; h < H1; h++)
#pragma unroll
    for (int q = 0; q < 4; q++) acc[h][q] = 0.f;

  const int j0 = rowstart[n], j1 = rowstart[n + 1];
  int j = j0;
  for (; j + 4 <= j1; j += 4) {
    int sidx[4];
    float4 wv[4], xv[4];
#pragma unroll
    for (int u = 0; u < 4; u++) sidx[u] = csr_src[j + u];
#pragma unroll
    for (int u = 0; u < 4; u++) wv[u] = *(const float4*)&evs[(size_t)(j + u) * H1];
#pragma unroll
    for (int u = 0; u < 4; u++)
      xv[u] = *(const float4*)(x + (size_t)sidx[u] * IN_DIM + f0);
#pragma unroll
    for (int u = 0; u < 4; u++) {
      const float* pw = (const float*)&wv[u];
#pragma unroll
      for (int h = 0; h < H1; h++) {
        acc[h][0] = fmaf(pw[h], xv[u].x, acc[h][0]);
        acc[h][1] = fmaf(pw[h], xv[u].y, acc[h][1]);
        acc[h][2] = fmaf(pw[h], xv[u].z, acc[h][2]);
        acc[h][3] = fmaf(pw[h], xv[u].w, acc[h][3]);
      }
    }
  }
  for (; j < j1; j++) {
    int s = csr_src[j];
    float4 wv = *(const float4*)&evs[(size_t)j * H1];
    float4 xv = *(const float4*)(x + (size_t)s * IN_DIM + f0);
    const float* pw = (const float*)&wv;
#pragma unroll
    for (int h = 0; h < H1; h++) {
      acc[h][0] = fmaf(pw[h], xv.x, acc[h][0]);
      acc[h][1] = fmaf(pw[h], xv.y, acc[h][1]);
      acc[h][2] = fmaf(pw[h], xv.z, acc[h][2]);
      acc[h][3] = fmaf(pw[h], xv.w, acc[h][3]);
    }
  }

#pragma unroll
  for (int h = 0; h < H1; h++) {
    f16x4 h4, l4;
#pragma unroll
    for (int q = 0; q < 4; q++) {
      float o = acc[h][q] * inv[h];
      _Float16 hv = (_Float16)o;
      h4[q] = hv;
      l4[q] = (_Float16)(o - (float)hv);
    }
    *(f16x4*)&ohi[(size_t)n * (H1 * IN_DIM) + h * IN_DIM + f0] = h4;
    *(f16x4*)&olo[(size_t)n * (H1 * IN_DIM) + h * IN_DIM + f0] = l4;
  }
}

// ---------------- layer-2 aggregation: out[n,:] = (sum ev*h3[src,:])/denom + b ----
template <int FT>
__global__ __launch_bounds__(256) void aggregate_k(
    const float* __restrict__ hsrc, const float* __restrict__ evs,
    const float* __restrict__ denom, const float* __restrict__ bias,
    const int* __restrict__ rowstart, const int* __restrict__ csr_src,
    float* __restrict__ out, int Hh, int C) {
  const int n = blockIdx.x;
  const int t = threadIdx.x;
  const int F = Hh * C;
  const int f0 = t * FT;
  const int hh = f0 / C;
  const float inv = 1.f / (denom[n * Hh + hh] + 1e-16f);
  float acc[FT];
#pragma unroll
  for (int i = 0; i < FT; i++) acc[i] = 0.f;
  const int j0 = rowstart[n], j1 = rowstart[n + 1];

  constexpr int UN = 8;
  int j = j0;
  for (; j + UN <= j1; j += UN) {
    int   sidx[UN];
    float wv[UN];
#pragma unroll
    for (int u = 0; u < UN; u++) sidx[u] = csr_src[j + u];
#pragma unroll
    for (int u = 0; u < UN; u++) wv[u] = evs[(size_t)(j + u) * Hh + hh];
    float4 va[UN][FT / 4];
#pragma unroll
    for (int u = 0; u < UN; u++) {
      const float* hp = hsrc + (size_t)sidx[u] * F + f0;
#pragma unroll
      for (int q = 0; q < FT / 4; q++) va[u][q] = *(const float4*)(hp + q * 4);
    }
#pragma unroll
    for (int u = 0; u < UN; u++)
#pragma unroll
      for (int q = 0; q < FT / 4; q++) {
        acc[q * 4 + 0] = fmaf(wv[u], va[u][q].x, acc[q * 4 + 0]);
        acc[q * 4 + 1] = fmaf(wv[u], va[u][q].y, acc[q * 4 + 1]);
        acc[q * 4 + 2] = fmaf(wv[u], va[u][q].z, acc[q * 4 + 2]);
        acc[q * 4 + 3] = fmaf(wv[u], va[u][q].w, acc[q * 4 + 3]);
      }
  }
  for (; j < j1; j++) {
    int s = csr_src[j];
    float wgt = evs[(size_t)j * Hh + hh];
    const float* hp = hsrc + (size_t)s * F + f0;
#pragma unroll
    for (int q = 0; q < FT / 4; q++) {
      float4 v = *(const float4*)(hp + q * 4);
      acc[q * 4 + 0] = fmaf(wgt, v.x, acc[q * 4 + 0]);
      acc[q * 4 + 1] = fmaf(wgt, v.y, acc[q * 4 + 1]);
      acc[q * 4 + 2] = fmaf(wgt, v.z, acc[q * 4 + 2]);
      acc[q * 4 + 3] = fmaf(wgt, v.w, acc[q * 4 + 3]);
    }
  }
#pragma unroll
  for (int i = 0; i < FT; i++)
    out[(size_t)n * F + f0 + i] = acc[i] * inv + bias[f0 + i];
}

// ---------------- launch ----------------
extern "C" void kernel_launch(void* const* d_in, const int* in_sizes, int n_in,
                              void* d_out, int out_size, void* d_ws, size_t ws_size,
                              hipStream_t stream) {
  const float* x   = (const float*)d_in[0];
  const int*   ei  = (const int*)d_in[1];   // [2, 160000]; JAX x64 off -> int32
  const float* W1  = (const float*)d_in[2];
  const float* as1 = (const float*)d_in[3];
  const float* ad1 = (const float*)d_in[4];
  const float* b1  = (const float*)d_in[5];
  const float* W2  = (const float*)d_in[6];
  const float* as2 = (const float*)d_in[7];
  const float* ad2 = (const float*)d_in[8];
  const float* b2  = (const float*)d_in[9];
  float* out = (float*)d_out;

  char* p = (char*)d_ws;
  auto alloc = [&](size_t bytes) {
    char* r = p;
    p += (bytes + 255) & ~(size_t)255;
    return r;
  };
  _Float16* xahi  = (_Float16*)alloc((size_t)N_NODES * H1 * IN_DIM * 2);  // 61.4 MB
  _Float16* xalo  = (_Float16*)alloc((size_t)N_NODES * H1 * IN_DIM * 2);
  _Float16* W1hi  = (_Float16*)alloc((size_t)IN_DIM * F1 * 2);            // [F1][IN_DIM]
  _Float16* W1lo  = (_Float16*)alloc((size_t)IN_DIM * F1 * 2);
  _Float16* W2hi  = (_Float16*)alloc((size_t)F1 * C2 * 2);                // [C2][F1]
  _Float16* W2lo  = (_Float16*)alloc((size_t)F1 * C2 * 2);
  _Float16* h2hi  = (_Float16*)alloc((size_t)N_NODES * F1 * 2);           // 41 MB
  _Float16* h2lo  = (_Float16*)alloc((size_t)N_NODES * F1 * 2);
  float*    ws1   = (float*)alloc((size_t)H1 * IN_DIM * 4);
  float*    wd1   = (float*)alloc((size_t)H1 * IN_DIM * 4);
  float*    als   = (float*)alloc((size_t)N_NODES * H1 * 4);
  float*    ald   = (float*)alloc((size_t)N_NODES * H1 * 4);
  unsigned* menc  = (unsigned*)alloc((size_t)N_NODES * H1 * 4);
  float*    denom = (float*)alloc((size_t)N_NODES * H1 * 4);
  float*    ev    = (float*)alloc((size_t)E_TOT * H1 * 4);
  float*    evs   = (float*)alloc((size_t)E_TOT * H1 * 4);
  int*      count    = (int*)alloc((size_t)N_NODES * 4);
  int*      rowstart = (int*)alloc((size_t)(N_NODES + 1) * 4);
  int*      cursor   = (int*)alloc((size_t)N_NODES * 4);
  int*      csr_src  = (int*)alloc((size_t)E_TOT * 4);
  int*      csr_pos  = (int*)alloc((size_t)E_TOT * 4);
  float*    h3 = (float*)xahi;  // xa dead after GEMM1; alias (30.7 <= 61.4 MB)

  const int EB = (E_TOT + 255) / 256;
  const int MT = (N_NODES + 127) / 128;   // 79 M-tiles

  // CSR by destination (same graph both layers)
  hipMemsetAsync(count, 0, (size_t)N_NODES * 4, stream);
  hipMemsetAsync(cursor, 0, (size_t)N_NODES * 4, stream);
  hist_k<<<EB, 256, 0, stream>>>(ei, count);
  scan_k<<<1, 1024, 0, stream>>>(count, rowstart, N_NODES, E_TOT);
  scatter_k<<<EB, 256, 0, stream>>>(ei, rowstart, cursor, csr_src, csr_pos);

  // weight conversions + projected attn vectors
  tsplit_k<<<dim3(F1 / 32, IN_DIM / 32), dim3(32, 8), 0, stream>>>(W1, W1hi, W1lo,
                                                                   IN_DIM, F1);
  tsplit_k<<<dim3(C2 / 32, F1 / 32), dim3(32, 8), 0, stream>>>(W2, W2hi, W2lo,
                                                               F1, C2);
  proj_attn_k<<<(H1 * IN_DIM * 64) / 256, 256, 0, stream>>>(W1, as1, ad1, ws1, wd1);

  // ---- layer 1 (aggregate-then-project) ----
  logits1_k<<<(N_NODES * 64 + 255) / 256, 256, 0, stream>>>(x, ws1, wd1, als, ald);
  hipMemsetAsync(menc, 0, (size_t)N_NODES * H1 * 4, stream);
  hipMemsetAsync(denom, 0, (size_t)N_NODES * H1 * 4, stream);
  edge_max_k<<<(E_TOT * H1 + 255) / 256, 256, 0, stream>>>(ei, als, ald, ev, menc, H1);
  edge_exp_k<<<(E_TOT * H1 + 255) / 256, 256, 0, stream>>>(ei, menc, ev, csr_pos,
                                                           evs, denom, H1);
  aggregate_x_k<<<N_NODES, 192, 0, stream>>>(x, evs, denom, rowstart, csr_src,
                                             xahi, xalo);
  // h2 = ELU(xa @ W1 + b1), written as f16 hi/lo
  {
    const int nbx = F1 / 128, nwg = nbx * MT;
    gemm_sf16<true><<<nwg, 256, 0, stream>>>(
        xahi, xalo, W1hi, W1lo, N_NODES, F1, IN_DIM, H1 * IN_DIM, C1, nbx, nwg,
        nullptr, b1, h2hi, h2lo, nullptr, nullptr, nullptr, nullptr, 0, C1);
  }

  // ---- layer 2 (project-then-aggregate, fused logits) ----
  hipMemsetAsync(als, 0, (size_t)N_NODES * 4, stream);
  hipMemsetAsync(ald, 0, (size_t)N_NODES * 4, stream);
  {
    const int nbx = C2 / 128, nwg = nbx * MT;
    gemm_sf16<false><<<nwg, 256, 0, stream>>>(
        h2hi, h2lo, W2hi, W2lo, N_NODES, C2, F1, F1, 1 << 30, nbx, nwg,
        h3, nullptr, nullptr, nullptr, as2, ad2, als, ald, 1, C2);
  }
  hipMemsetAsync(menc, 0, (size_t)N_NODES * 4, stream);
  hipMemsetAsync(denom, 0, (size_t)N_NODES * 4, stream);
  edge_max_k<<<EB, 256, 0, stream>>>(ei, als, ald, ev, menc, 1);
  edge_exp_k<<<EB, 256, 0, stream>>>(ei, menc, ev, csr_pos, evs, denom, 1);
  aggregate_k<4><<<N_NODES, 192, 0, stream>>>(h3, evs, denom, b2, rowstart,
                                              csr_src, out, 1, C2);
}